// Round 11
// baseline (6190.398 us; speedup 1.0000x reference)
//
#include <hip/hip_runtime.h>

#define T_DIM 1024
#define B_DIM 128
#define I_DIM 512
#define H_DIM 1024
#define O_DIM 512
#define TC 64
#define NCHUNK (T_DIM / TC)

typedef _Float16 half8 __attribute__((ext_vector_type(8)));
typedef _Float16 half4v __attribute__((ext_vector_type(4)));
typedef float floatx4 __attribute__((ext_vector_type(4)));
typedef unsigned int uint4v __attribute__((ext_vector_type(4)));

__device__ __forceinline__ void gload_lds16(const void* g, void* l) {
  __builtin_amdgcn_global_load_lds(
      (const __attribute__((address_space(1))) void*)g,
      (__attribute__((address_space(3))) void*)l, 16, 0, 0);
}

__device__ __forceinline__ float sigmoidf_(float x) {
  return 1.f / (1.f + __expf(-x));
}
__device__ __forceinline__ float tanhf_(float x) {
  float e = __expf(fminf(-2.f * x, 60.f));
  return (1.f - e) / (1.f + e);
}

// ---------------- converts ----------------
__global__ __launch_bounds__(256) void k_cvt(const float* __restrict__ s,
                                             _Float16* __restrict__ d, int n4) {
  int i = blockIdx.x * 256 + threadIdx.x;
  if (i < n4) {
    float4 v = ((const float4*)s)[i];
    half4v h = {(_Float16)v.x, (_Float16)v.y, (_Float16)v.z, (_Float16)v.w};
    ((half4v*)d)[i] = h;
  }
}

// x:(B,T,I) fp32 -> x16:(TC*B, I) fp16 rows (tl*128+b)
__global__ __launch_bounds__(256) void k_cvt_x(const float* __restrict__ x,
                                               _Float16* __restrict__ x16, int t0) {
  int i = blockIdx.x * 256 + threadIdx.x;  // per float4
  int i4 = i & 127;
  int row = i >> 7;           // 0..TC*128-1
  int b = row & 127, tl = row >> 7;
  float4 v = ((const float4*)(x + ((size_t)b * T_DIM + t0 + tl) * I_DIM))[i4];
  half4v h = {(_Float16)v.x, (_Float16)v.y, (_Float16)v.z, (_Float16)v.w};
  ((half4v*)(x16 + (size_t)row * I_DIM))[i4] = h;
}

__global__ __launch_bounds__(256) void build_bcat(const float* __restrict__ a,
                                                  const float* __restrict__ b,
                                                  const float* __restrict__ c,
                                                  const float* __restrict__ d,
                                                  float* __restrict__ o) {
  int i = blockIdx.x * 256 + threadIdx.x;
  if (i < 4096) {
    const float* p = (i < 1024) ? a : (i < 2048) ? b : (i < 3072) ? c : d;
    o[i] = p[i & 1023];
  }
}

// ---------------- GEMM: C = A[M][K] * B[N][K]^T + bias ----------------
// MODE 0: fp16 out row-major [M][N].  MODE 1: fp32 out scattered to (b,t,o).
template <int MODE>
__global__ __launch_bounds__(256) void gemm_f16(
    const _Float16* __restrict__ A, const _Float16* __restrict__ B,
    const float* __restrict__ bias, _Float16* __restrict__ C16,
    float* __restrict__ C32, int M, int N, int K, int t0) {
  __shared__ __align__(16) _Float16 As[128 * 64];
  __shared__ __align__(16) _Float16 Bs[128 * 64];
  const int tid = threadIdx.x, lane = tid & 63, wv = tid >> 6;
  const int wm = wv >> 1, wn = wv & 1;
  const int lj = lane & 15, lk = lane >> 4;
  const size_t rowA0 = (size_t)blockIdx.y * 128, colB0 = (size_t)blockIdx.x * 128;
  floatx4 acc[4][4] = {};
  for (int kb = 0; kb < K; kb += 64) {
    __syncthreads();
#pragma unroll
    for (int i = 0; i < 4; ++i) {
      int q = i * 256 + tid;
      int r = q >> 3, c = q & 7;
      gload_lds16(A + (rowA0 + r) * (size_t)K + kb + c * 8, As + (size_t)(i * 4 + wv) * 512);
    }
#pragma unroll
    for (int i = 0; i < 4; ++i) {
      int q = i * 256 + tid;
      int r = q >> 3, c = q & 7;
      gload_lds16(B + (colB0 + r) * (size_t)K + kb + c * 8, Bs + (size_t)(i * 4 + wv) * 512);
    }
    __syncthreads();
#pragma unroll
    for (int ks = 0; ks < 2; ++ks) {
      half8 af[4], bf[4];
#pragma unroll
      for (int am = 0; am < 4; ++am)
        af[am] = *(const half8*)(As + (wm * 64 + am * 16 + lj) * 64 + ks * 32 + lk * 8);
#pragma unroll
      for (int bn = 0; bn < 4; ++bn)
        bf[bn] = *(const half8*)(Bs + (wn * 64 + bn * 16 + lj) * 64 + ks * 32 + lk * 8);
#pragma unroll
      for (int am = 0; am < 4; ++am)
#pragma unroll
        for (int bn = 0; bn < 4; ++bn)
          acc[am][bn] = __builtin_amdgcn_mfma_f32_16x16x32_f16(af[am], bf[bn], acc[am][bn], 0, 0, 0);
    }
  }
#pragma unroll
  for (int am = 0; am < 4; ++am)
#pragma unroll
    for (int bn = 0; bn < 4; ++bn)
#pragma unroll
      for (int rr = 0; rr < 4; ++rr) {
        size_t grow = rowA0 + wm * 64 + am * 16 + lk * 4 + rr;
        size_t gcol = colB0 + wn * 64 + bn * 16 + lj;
        float v = acc[am][bn][rr] + bias[gcol];
        if constexpr (MODE == 0) {
          C16[grow * (size_t)N + gcol] = (_Float16)v;
        } else {
          size_t tl = grow >> 7, b = grow & 127;
          C32[b * (size_t)(T_DIM * O_DIM) + (t0 + tl) * (size_t)O_DIM + gcol] = v;
        }
      }
}

// ---------------- GRU scan over one T-chunk ----------------
// R3 protocol (proven): grid 256 = 8 bgroups(16 rows) x 32 jslices; block 384
// = 6 waves (gate g=wv%3, jh=wv/3); stagers waves0-3, publisher wave0, poll
// wave5; barriers A0,A1,B,C,D. All h traffic sc0+sc1 (fabric-coherent).
// NEW vs R3 (only two changes):
//  (1) split-half stage: waves 0,2 hold k<512 chunks, waves 1,3 k>=512
//      (chunk col = tid&127). Waves 1,3 defer their drain+LDS-write past
//      barrier A0 so half1's fabric RTT hides under MFMA of half0.
//  (2) dual accumulators break the 32-long dependent MFMA chain.
__global__ __launch_bounds__(384) void scan_kernel(
    const _Float16* __restrict__ rznx,   // [TC][128][4096]
    const _Float16* __restrict__ Whcat,  // [3][1024][1024]
    const float* __restrict__ bhr, const float* __restrict__ bhz,
    const float* __restrict__ bhn,
    _Float16* __restrict__ h16,  // [2][128][1024]
    float* __restrict__ h32,     // [128][1024]
    _Float16* __restrict__ hs16, // [TC][128][1024]
    int* __restrict__ flags,     // [8][32] flags, each padded to 128B
    int chunk) {
  __shared__ __align__(16) _Float16 hlds[16 * 1024];
  __shared__ float exch[2][2][16 * 17];
  __shared__ __align__(16) _Float16 hout[16][32];
  const int tid = threadIdx.x, lane = tid & 63, wv = tid >> 6;
  const int g = wv % 3, jh = wv / 3;
  const int bg = blockIdx.x & 7, js = blockIdx.x >> 3;
  const int b0 = bg * 16;
  const int jbase = js * 32 + jh * 16;
  const int lj = lane & 15, lk = lane >> 4;
  const int jcol = jbase + lj;

  // W fragments resident in VGPRs for the whole chunk
  half8 wf[32];
  {
    const _Float16* wb = Whcat + ((size_t)g * 1024 + jcol) * 1024 + lk * 8;
#pragma unroll
    for (int ks = 0; ks < 32; ++ks) wf[ks] = *(const half8*)(wb + ks * 32);
  }
  const float* bh = (g == 0) ? bhr : (g == 1) ? bhz : bhn;
  const float biasg = bh[jcol];
  float hown[4];
  if (g == 1) {
#pragma unroll
    for (int r = 0; r < 4; ++r) hown[r] = h32[(size_t)(b0 + lk * 4 + r) * 1024 + jcol];
  }
  const bool stager = (tid < 256);
  const bool half0 = stager && ((tid & 127) < 64);  // uniform per wave
  int cur = 0;
  for (int t = 0; t < TC; ++t) {
    const int gs = chunk * TC + t;  // global step index (monotonic)
    // ---- prefetch x-side gate inputs for THIS step (independent of h) ----
    const _Float16* xg = rznx + ((size_t)t * 128 + b0) * 4096 + g * 1024 + jcol;
    float xv[4];
#pragma unroll
    for (int r = 0; r < 4; ++r) xv[r] = (float)xg[(size_t)(lk * 4 + r) * 4096];
    float nxv[4];
    if (g == 1) {
#pragma unroll
      for (int r = 0; r < 4; ++r)
        nxv[r] = (float)rznx[((size_t)t * 128 + b0 + lk * 4 + r) * 4096 + 2048 + jcol];
    }
    // ---- stage h16[cur]: issue all loads; half0 waves drain+write now ----
    uint4v vv[8];
    if (stager) {
      const _Float16* hsrc = h16 + (size_t)cur * (128 * 1024) + (size_t)b0 * 1024;
      const char* ap[8];
#pragma unroll
      for (int i = 0; i < 8; ++i) {
        int q = tid + i * 256;  // 0..2047 ; col-group c = q&127 == tid&127
        int b = q >> 7, c = q & 127;
        ap[i] = (const char*)(hsrc + b * 1024 + c * 8);
      }
#pragma unroll
      for (int i = 0; i < 8; ++i)
        asm volatile("global_load_dwordx4 %0, %1, off sc0 sc1"
                     : "=v"(vv[i]) : "v"(ap[i]));
      if (half0) {
        asm volatile("s_waitcnt vmcnt(0)" ::: "memory");
#pragma unroll
        for (int i = 0; i < 8; ++i) {
          int q = tid + i * 256;
          int b = q >> 7, c = q & 127;
          *(uint4v*)((char*)hlds + b * 2048 + ((c ^ (b & 7)) * 16)) = vv[i];
        }
      }
    }
    __syncthreads();  // (A0) half0 staged; half1 loads in flight
    if (stager && !half0) {
      asm volatile("s_waitcnt vmcnt(0)" ::: "memory");
#pragma unroll
      for (int i = 0; i < 8; ++i) {
        int q = tid + i * 256;
        int b = q >> 7, c = q & 127;
        *(uint4v*)((char*)hlds + b * 2048 + ((c ^ (b & 7)) * 16)) = vv[i];
      }
    }
    floatx4 acc0 = {0.f, 0.f, 0.f, 0.f}, acc1 = {0.f, 0.f, 0.f, 0.f};
#pragma unroll
    for (int ks = 0; ks < 16; ks += 2) {
      int c0 = ks * 4 + lk, c1 = (ks + 1) * 4 + lk;
      int b = lj;
      half8 af0 = *(const half8*)((const char*)hlds + b * 2048 + ((c0 ^ (b & 7)) * 16));
      half8 af1 = *(const half8*)((const char*)hlds + b * 2048 + ((c1 ^ (b & 7)) * 16));
      acc0 = __builtin_amdgcn_mfma_f32_16x16x32_f16(af0, wf[ks], acc0, 0, 0, 0);
      acc1 = __builtin_amdgcn_mfma_f32_16x16x32_f16(af1, wf[ks + 1], acc1, 0, 0, 0);
    }
    __syncthreads();  // (A1) half1 staged (written concurrently with MFMA above)
#pragma unroll
    for (int ks = 16; ks < 32; ks += 2) {
      int c0 = ks * 4 + lk, c1 = (ks + 1) * 4 + lk;
      int b = lj;
      half8 af0 = *(const half8*)((const char*)hlds + b * 2048 + ((c0 ^ (b & 7)) * 16));
      half8 af1 = *(const half8*)((const char*)hlds + b * 2048 + ((c1 ^ (b & 7)) * 16));
      acc0 = __builtin_amdgcn_mfma_f32_16x16x32_f16(af0, wf[ks], acc0, 0, 0, 0);
      acc1 = __builtin_amdgcn_mfma_f32_16x16x32_f16(af1, wf[ks + 1], acc1, 0, 0, 0);
    }
    floatx4 acc = acc0 + acc1;
    float zv[4] = {0.f, 0.f, 0.f, 0.f};
    if (g == 0) {
#pragma unroll
      for (int r = 0; r < 4; ++r)
        exch[jh][0][(lk * 4 + r) * 17 + lj] = sigmoidf_(acc[r] + biasg + xv[r]);
    } else if (g == 2) {
#pragma unroll
      for (int r = 0; r < 4; ++r)
        exch[jh][1][(lk * 4 + r) * 17 + lj] = acc[r] + biasg;
    } else {
#pragma unroll
      for (int r = 0; r < 4; ++r) zv[r] = sigmoidf_(acc[r] + biasg + xv[r]);
    }
    __syncthreads();  // (B) exch ready
    if (g == 1) {
#pragma unroll
      for (int r = 0; r < 4; ++r) {
        float rr = exch[jh][0][(lk * 4 + r) * 17 + lj];
        float np = exch[jh][1][(lk * 4 + r) * 17 + lj];
        float n = tanhf_(nxv[r] + rr * np);
        float hn = (1.f - zv[r]) * n + zv[r] * hown[r];
        hown[r] = hn;
        hout[lk * 4 + r][jh * 16 + lj] = (_Float16)hn;
      }
    }
    __syncthreads();  // (C) hout ready
    if (wv == 0) {
      // coalesced fabric-coherent h16 store + plain hs16 store, then flag
      int row = lane >> 2, c = lane & 3;
      uint4v hv = *(const uint4v*)((const char*)hout + row * 64 + c * 16);
      char* p1 = (char*)(h16 + (size_t)(cur ^ 1) * (128 * 1024) +
                         (size_t)(b0 + row) * 1024 + js * 32 + c * 8);
      asm volatile("global_store_dwordx4 %0, %1, off sc0 sc1"
                   :: "v"(p1), "v"(hv) : "memory");
      _Float16* p2 = hs16 + ((size_t)t * 128 + b0 + row) * 1024 + js * 32 + c * 8;
      *(uint4v*)p2 = hv;
      asm volatile("s_waitcnt vmcnt(0)" ::: "memory");
      if (lane == 0) {
        int* fp = flags + ((size_t)bg * 32 + js) * 32;
        int val = gs + 1;
        asm volatile("global_store_dword %0, %1, off sc0 sc1"
                     :: "v"(fp), "v"(val) : "memory");
      }
    } else if (wv == 5) {
      // poll all 32 flags of this bgroup (lanes 32-63 mirror lanes 0-31)
      const int* fp = flags + ((size_t)bg * 32 + (lane & 31)) * 32;
      const int target = gs + 1;
      int spin = 0;
      while (true) {
        int v;
        asm volatile("global_load_dword %0, %1, off sc0 sc1\n\ts_waitcnt vmcnt(0)"
                     : "=v"(v) : "v"(fp) : "memory");
        if (__all(v >= target)) break;
        __builtin_amdgcn_s_sleep(1);
        if (++spin > (1 << 17)) break;  // safety valve vs hang
      }
    }
    __syncthreads();  // (D) all 32 blocks of bgroup have published h_{t+1}
    cur ^= 1;
  }
  if (g == 1) {
#pragma unroll
    for (int r = 0; r < 4; ++r) h32[(size_t)(b0 + lk * 4 + r) * 1024 + jcol] = hown[r];
  }
}

// ---------------- LayerNorm(hs + skip) -> fp16 ----------------
__global__ __launch_bounds__(256) void ln_kernel(
    const _Float16* __restrict__ hs, const _Float16* __restrict__ rz,
    const float* __restrict__ gamma, const float* __restrict__ beta,
    _Float16* __restrict__ outp) {
  const int row = blockIdx.x, tid = threadIdx.x;
  const int lane = tid & 63, wv = tid >> 6;
  half4v hv = *(const half4v*)(hs + (size_t)row * 1024 + tid * 4);
  half4v sv = *(const half4v*)(rz + (size_t)row * 4096 + 3072 + tid * 4);
  float v[4];
  float s = 0.f, s2 = 0.f;
#pragma unroll
  for (int j = 0; j < 4; ++j) {
    v[j] = (float)hv[j] + (float)sv[j];
    s += v[j];
    s2 += v[j] * v[j];
  }
#pragma unroll
  for (int o = 32; o > 0; o >>= 1) {
    s += __shfl_xor(s, o, 64);
    s2 += __shfl_xor(s2, o, 64);
  }
  __shared__ float ps[4][2];
  if (lane == 0) { ps[wv][0] = s; ps[wv][1] = s2; }
  __syncthreads();
  s = ps[0][0] + ps[1][0] + ps[2][0] + ps[3][0];
  s2 = ps[0][1] + ps[1][1] + ps[2][1] + ps[3][1];
  const float mu = s * (1.f / 1024.f);
  const float var = s2 * (1.f / 1024.f) - mu * mu;
  const float rstd = rsqrtf(var + 1e-5f);
  half4v ov;
#pragma unroll
  for (int j = 0; j < 4; ++j)
    ov[j] = (_Float16)((v[j] - mu) * rstd * gamma[tid * 4 + j] + beta[tid * 4 + j]);
  *(half4v*)(outp + (size_t)row * 1024 + tid * 4) = ov;
}

// ---------------- host ----------------
extern "C" void kernel_launch(void* const* d_in, const int* in_sizes, int n_in,
                              void* d_out, int out_size, void* d_ws, size_t ws_size,
                              hipStream_t stream) {
  const float* x     = (const float*)d_in[0];
  const float* Wir   = (const float*)d_in[1];
  const float* bir   = (const float*)d_in[2];
  const float* Whr   = (const float*)d_in[3];
  const float* bhr   = (const float*)d_in[4];
  const float* Wiz   = (const float*)d_in[5];
  const float* biz   = (const float*)d_in[6];
  const float* Whz   = (const float*)d_in[7];
  const float* bhz   = (const float*)d_in[8];
  const float* Win   = (const float*)d_in[9];
  const float* bin_  = (const float*)d_in[10];
  const float* Whn   = (const float*)d_in[11];
  const float* bhn   = (const float*)d_in[12];
  const float* Wskip = (const float*)d_in[13];
  const float* bskip = (const float*)d_in[14];
  const float* gamma = (const float*)d_in[15];
  const float* beta  = (const float*)d_in[16];
  const float* Wout  = (const float*)d_in[17];
  const float* bout  = (const float*)d_in[18];
  float* out = (float*)d_out;

  char* ws = (char*)d_ws;
  size_t off = 0;
  auto alloc = [&](size_t bytes) -> char* {
    char* p = ws + off;
    off += (bytes + 255) & ~(size_t)255;
    return p;
  };
  _Float16* x16    = (_Float16*)alloc((size_t)TC * 128 * 512 * 2);
  _Float16* Wcat   = (_Float16*)alloc((size_t)4096 * 512 * 2);
  _Float16* Whcat  = (_Float16*)alloc((size_t)3072 * 1024 * 2);
  _Float16* Wout16 = (_Float16*)alloc((size_t)512 * 1024 * 2);
  float*    bcat   = (float*)alloc(4096 * 4);
  _Float16* rznx   = (_Float16*)alloc((size_t)TC * 128 * 4096 * 2);
  _Float16* h16    = (_Float16*)alloc((size_t)2 * 128 * 1024 * 2);
  float*    h32    = (float*)alloc((size_t)128 * 1024 * 4);
  _Float16* hs16   = (_Float16*)alloc((size_t)TC * 128 * 1024 * 2);
  _Float16* normed = (_Float16*)alloc((size_t)TC * 128 * 1024 * 2);
  int*      flags  = (int*)alloc(8 * 32 * 32 * sizeof(int));

  k_cvt<<<512, 256, 0, stream>>>(Wir, Wcat + 0 * 524288, 131072);
  k_cvt<<<512, 256, 0, stream>>>(Wiz, Wcat + 1 * 524288, 131072);
  k_cvt<<<512, 256, 0, stream>>>(Win, Wcat + 2 * 524288, 131072);
  k_cvt<<<512, 256, 0, stream>>>(Wskip, Wcat + 3 * 524288, 131072);
  k_cvt<<<1024, 256, 0, stream>>>(Whr, Whcat + 0 * 1048576, 262144);
  k_cvt<<<1024, 256, 0, stream>>>(Whz, Whcat + 1 * 1048576, 262144);
  k_cvt<<<1024, 256, 0, stream>>>(Whn, Whcat + 2 * 1048576, 262144);
  k_cvt<<<512, 256, 0, stream>>>(Wout, Wout16, 131072);
  build_bcat<<<16, 256, 0, stream>>>(bir, biz, bin_, bskip, bcat);
  hipMemsetAsync(h16, 0, (size_t)2 * 128 * 1024 * 2, stream);
  hipMemsetAsync(h32, 0, (size_t)128 * 1024 * 4, stream);
  hipMemsetAsync(flags, 0, 8 * 32 * 32 * sizeof(int), stream);

  for (int c = 0; c < NCHUNK; ++c) {
    int t0 = c * TC;
    k_cvt_x<<<(TC * 128 * 512 / 4) / 256, 256, 0, stream>>>(x, x16, t0);
    gemm_f16<0><<<dim3(4096 / 128, TC * 128 / 128), 256, 0, stream>>>(
        x16, Wcat, bcat, rznx, nullptr, TC * 128, 4096, 512, 0);
    scan_kernel<<<256, 384, 0, stream>>>(rznx, Whcat, bhr, bhz, bhn, h16, h32, hs16, flags, c);
    ln_kernel<<<TC * 128, 256, 0, stream>>>(hs16, rznx, gamma, beta, normed);
    gemm_f16<1><<<dim3(512 / 128, TC * 128 / 128), 256, 0, stream>>>(
        normed, Wout16, bout, nullptr, out, TC * 128, 512, 1024, t0);
  }
}

// Round 12
// 5499.067 us; speedup vs baseline: 1.1257x; 1.1257x over previous
//
#include <hip/hip_runtime.h>

#define T_DIM 1024
#define B_DIM 128
#define I_DIM 512
#define H_DIM 1024
#define O_DIM 512
#define TC 64
#define NCHUNK (T_DIM / TC)

typedef _Float16 half8 __attribute__((ext_vector_type(8)));
typedef _Float16 half4v __attribute__((ext_vector_type(4)));
typedef float floatx4 __attribute__((ext_vector_type(4)));
typedef unsigned int uint4v __attribute__((ext_vector_type(4)));

__device__ __forceinline__ void gload_lds16(const void* g, void* l) {
  __builtin_amdgcn_global_load_lds(
      (const __attribute__((address_space(1))) void*)g,
      (__attribute__((address_space(3))) void*)l, 16, 0, 0);
}

__device__ __forceinline__ float sigmoidf_(float x) {
  return 1.f / (1.f + __expf(-x));
}
__device__ __forceinline__ float tanhf_(float x) {
  float e = __expf(fminf(-2.f * x, 60.f));
  return (1.f - e) / (1.f + e);
}

// ---------------- converts ----------------
__global__ __launch_bounds__(256) void k_cvt(const float* __restrict__ s,
                                             _Float16* __restrict__ d, int n4) {
  int i = blockIdx.x * 256 + threadIdx.x;
  if (i < n4) {
    float4 v = ((const float4*)s)[i];
    half4v h = {(_Float16)v.x, (_Float16)v.y, (_Float16)v.z, (_Float16)v.w};
    ((half4v*)d)[i] = h;
  }
}

// x:(B,T,I) fp32 -> x16:(TC*B, I) fp16 rows (tl*128+b)
__global__ __launch_bounds__(256) void k_cvt_x(const float* __restrict__ x,
                                               _Float16* __restrict__ x16, int t0) {
  int i = blockIdx.x * 256 + threadIdx.x;  // per float4
  int i4 = i & 127;
  int row = i >> 7;           // 0..TC*128-1
  int b = row & 127, tl = row >> 7;
  float4 v = ((const float4*)(x + ((size_t)b * T_DIM + t0 + tl) * I_DIM))[i4];
  half4v h = {(_Float16)v.x, (_Float16)v.y, (_Float16)v.z, (_Float16)v.w};
  ((half4v*)(x16 + (size_t)row * I_DIM))[i4] = h;
}

__global__ __launch_bounds__(256) void build_bcat(const float* __restrict__ a,
                                                  const float* __restrict__ b,
                                                  const float* __restrict__ c,
                                                  const float* __restrict__ d,
                                                  float* __restrict__ o) {
  int i = blockIdx.x * 256 + threadIdx.x;
  if (i < 4096) {
    const float* p = (i < 1024) ? a : (i < 2048) ? b : (i < 3072) ? c : d;
    o[i] = p[i & 1023];
  }
}

// ---------------- input GEMM: rznx = x16 @ Wcat^T + bcat (fp16 out) ----------------
__global__ __launch_bounds__(256) void gemm_f16(
    const _Float16* __restrict__ A, const _Float16* __restrict__ B,
    const float* __restrict__ bias, _Float16* __restrict__ C16,
    int M, int N, int K) {
  __shared__ __align__(16) _Float16 As[128 * 64];
  __shared__ __align__(16) _Float16 Bs[128 * 64];
  const int tid = threadIdx.x, lane = tid & 63, wv = tid >> 6;
  const int wm = wv >> 1, wn = wv & 1;
  const int lj = lane & 15, lk = lane >> 4;
  const size_t rowA0 = (size_t)blockIdx.y * 128, colB0 = (size_t)blockIdx.x * 128;
  floatx4 acc[4][4] = {};
  for (int kb = 0; kb < K; kb += 64) {
    __syncthreads();
#pragma unroll
    for (int i = 0; i < 4; ++i) {
      int q = i * 256 + tid;
      int r = q >> 3, c = q & 7;
      gload_lds16(A + (rowA0 + r) * (size_t)K + kb + c * 8, As + (size_t)(i * 4 + wv) * 512);
    }
#pragma unroll
    for (int i = 0; i < 4; ++i) {
      int q = i * 256 + tid;
      int r = q >> 3, c = q & 7;
      gload_lds16(B + (colB0 + r) * (size_t)K + kb + c * 8, Bs + (size_t)(i * 4 + wv) * 512);
    }
    __syncthreads();
#pragma unroll
    for (int ks = 0; ks < 2; ++ks) {
      half8 af[4], bf[4];
#pragma unroll
      for (int am = 0; am < 4; ++am)
        af[am] = *(const half8*)(As + (wm * 64 + am * 16 + lj) * 64 + ks * 32 + lk * 8);
#pragma unroll
      for (int bn = 0; bn < 4; ++bn)
        bf[bn] = *(const half8*)(Bs + (wn * 64 + bn * 16 + lj) * 64 + ks * 32 + lk * 8);
#pragma unroll
      for (int am = 0; am < 4; ++am)
#pragma unroll
        for (int bn = 0; bn < 4; ++bn)
          acc[am][bn] = __builtin_amdgcn_mfma_f32_16x16x32_f16(af[am], bf[bn], acc[am][bn], 0, 0, 0);
    }
  }
#pragma unroll
  for (int am = 0; am < 4; ++am)
#pragma unroll
    for (int bn = 0; bn < 4; ++bn)
#pragma unroll
      for (int rr = 0; rr < 4; ++rr) {
        size_t grow = rowA0 + wm * 64 + am * 16 + lk * 4 + rr;
        size_t gcol = colB0 + wn * 64 + bn * 16 + lj;
        C16[grow * (size_t)N + gcol] = (_Float16)(acc[am][bn][rr] + bias[gcol]);
      }
}

// ---------------- GRU scan over one T-chunk (R3, verbatim) ----------------
__global__ __launch_bounds__(384) void scan_kernel(
    const _Float16* __restrict__ rznx,   // [TC][128][4096]
    const _Float16* __restrict__ Whcat,  // [3][1024][1024]
    const float* __restrict__ bhr, const float* __restrict__ bhz,
    const float* __restrict__ bhn,
    _Float16* __restrict__ h16,  // [2][128][1024]  (fabric-coherent buffer)
    float* __restrict__ h32,     // [128][1024]
    _Float16* __restrict__ hs16, // [TC][128][1024]
    int* __restrict__ flags,     // [8][32] flags, each padded to 128B (32 ints)
    int chunk) {
  __shared__ __align__(16) _Float16 hlds[16 * 1024];
  __shared__ float exch[2][2][16 * 17];
  __shared__ __align__(16) _Float16 hout[16][32];
  const int tid = threadIdx.x, lane = tid & 63, wv = tid >> 6;
  const int g = wv % 3, jh = wv / 3;
  const int bg = blockIdx.x & 7, js = blockIdx.x >> 3;
  const int b0 = bg * 16;
  const int jbase = js * 32 + jh * 16;
  const int lj = lane & 15, lk = lane >> 4;
  const int jcol = jbase + lj;

  half8 wf[32];
  {
    const _Float16* wb = Whcat + ((size_t)g * 1024 + jcol) * 1024 + lk * 8;
#pragma unroll
    for (int ks = 0; ks < 32; ++ks) wf[ks] = *(const half8*)(wb + ks * 32);
  }
  const float* bh = (g == 0) ? bhr : (g == 1) ? bhz : bhn;
  const float biasg = bh[jcol];
  float hown[4];
  if (g == 1) {
#pragma unroll
    for (int r = 0; r < 4; ++r) hown[r] = h32[(size_t)(b0 + lk * 4 + r) * 1024 + jcol];
  }
  int cur = 0;
  for (int t = 0; t < TC; ++t) {
    const int gs = chunk * TC + t;
    const _Float16* xg = rznx + ((size_t)t * 128 + b0) * 4096 + g * 1024 + jcol;
    float xv[4];
#pragma unroll
    for (int r = 0; r < 4; ++r) xv[r] = (float)xg[(size_t)(lk * 4 + r) * 4096];
    float nxv[4];
    if (g == 1) {
#pragma unroll
      for (int r = 0; r < 4; ++r)
        nxv[r] = (float)rznx[((size_t)t * 128 + b0 + lk * 4 + r) * 4096 + 2048 + jcol];
    }
    if (tid < 256) {
      const _Float16* hsrc = h16 + (size_t)cur * (128 * 1024) + (size_t)b0 * 1024;
      uint4v vv[8];
      const char* ap[8];
#pragma unroll
      for (int i = 0; i < 8; ++i) {
        int q = tid + i * 256;
        int b = q >> 7, c = q & 127;
        ap[i] = (const char*)(hsrc + b * 1024 + c * 8);
      }
#pragma unroll
      for (int i = 0; i < 8; ++i)
        asm volatile("global_load_dwordx4 %0, %1, off sc0 sc1"
                     : "=v"(vv[i]) : "v"(ap[i]));
      asm volatile("s_waitcnt vmcnt(0)" ::: "memory");
#pragma unroll
      for (int i = 0; i < 8; ++i) {
        int q = tid + i * 256;
        int b = q >> 7, c = q & 127;
        *(uint4v*)((char*)hlds + b * 2048 + ((c ^ (b & 7)) * 16)) = vv[i];
      }
    }
    __syncthreads();  // (A) h staged
    floatx4 acc = {0.f, 0.f, 0.f, 0.f};
#pragma unroll
    for (int ks = 0; ks < 32; ++ks) {
      int c = ks * 4 + lk;
      int b = lj;
      half8 af = *(const half8*)((const char*)hlds + b * 2048 + ((c ^ (b & 7)) * 16));
      acc = __builtin_amdgcn_mfma_f32_16x16x32_f16(af, wf[ks], acc, 0, 0, 0);
    }
    float zv[4] = {0.f, 0.f, 0.f, 0.f};
    if (g == 0) {
#pragma unroll
      for (int r = 0; r < 4; ++r)
        exch[jh][0][(lk * 4 + r) * 17 + lj] = sigmoidf_(acc[r] + biasg + xv[r]);
    } else if (g == 2) {
#pragma unroll
      for (int r = 0; r < 4; ++r)
        exch[jh][1][(lk * 4 + r) * 17 + lj] = acc[r] + biasg;
    } else {
#pragma unroll
      for (int r = 0; r < 4; ++r) zv[r] = sigmoidf_(acc[r] + biasg + xv[r]);
    }
    __syncthreads();  // (B) exch ready
    if (g == 1) {
#pragma unroll
      for (int r = 0; r < 4; ++r) {
        float rr = exch[jh][0][(lk * 4 + r) * 17 + lj];
        float np = exch[jh][1][(lk * 4 + r) * 17 + lj];
        float n = tanhf_(nxv[r] + rr * np);
        float hn = (1.f - zv[r]) * n + zv[r] * hown[r];
        hown[r] = hn;
        hout[lk * 4 + r][jh * 16 + lj] = (_Float16)hn;
      }
    }
    __syncthreads();  // (C) hout ready
    if (wv == 0) {
      int row = lane >> 2, c = lane & 3;
      uint4v hv = *(const uint4v*)((const char*)hout + row * 64 + c * 16);
      char* p1 = (char*)(h16 + (size_t)(cur ^ 1) * (128 * 1024) +
                         (size_t)(b0 + row) * 1024 + js * 32 + c * 8);
      asm volatile("global_store_dwordx4 %0, %1, off sc0 sc1"
                   :: "v"(p1), "v"(hv) : "memory");
      _Float16* p2 = hs16 + ((size_t)t * 128 + b0 + row) * 1024 + js * 32 + c * 8;
      *(uint4v*)p2 = hv;
      asm volatile("s_waitcnt vmcnt(0)" ::: "memory");
      if (lane == 0) {
        int* fp = flags + ((size_t)bg * 32 + js) * 32;
        int val = gs + 1;
        asm volatile("global_store_dword %0, %1, off sc0 sc1"
                     :: "v"(fp), "v"(val) : "memory");
      }
    } else if (wv == 5) {
      const int* fp = flags + ((size_t)bg * 32 + (lane & 31)) * 32;
      const int target = gs + 1;
      int spin = 0;
      while (true) {
        int v;
        asm volatile("global_load_dword %0, %1, off sc0 sc1\n\ts_waitcnt vmcnt(0)"
                     : "=v"(v) : "v"(fp) : "memory");
        if (__all(v >= target)) break;
        __builtin_amdgcn_s_sleep(1);
        if (++spin > (1 << 17)) break;  // safety valve vs hang
      }
    }
    __syncthreads();  // (D)
    cur ^= 1;
  }
  if (g == 1) {
#pragma unroll
    for (int r = 0; r < 4; ++r) h32[(size_t)(b0 + lk * 4 + r) * 1024 + jcol] = hown[r];
  }
}

// ---------------- LN stats only: musig[row] = {mu, rstd} of (hs + skip) ----------------
__global__ __launch_bounds__(256) void ln_stats(
    const _Float16* __restrict__ hs, const _Float16* __restrict__ rz,
    float* __restrict__ musig) {
  const int row = blockIdx.x, tid = threadIdx.x;
  const int lane = tid & 63, wv = tid >> 6;
  half4v hv = *(const half4v*)(hs + (size_t)row * 1024 + tid * 4);
  half4v sv = *(const half4v*)(rz + (size_t)row * 4096 + 3072 + tid * 4);
  float s = 0.f, s2 = 0.f;
#pragma unroll
  for (int j = 0; j < 4; ++j) {
    float v = (float)hv[j] + (float)sv[j];
    s += v;
    s2 += v * v;
  }
#pragma unroll
  for (int o = 32; o > 0; o >>= 1) {
    s += __shfl_xor(s, o, 64);
    s2 += __shfl_xor(s2, o, 64);
  }
  __shared__ float ps[4][2];
  if (lane == 0) { ps[wv][0] = s; ps[wv][1] = s2; }
  __syncthreads();
  if (tid == 0) {
    s = ps[0][0] + ps[1][0] + ps[2][0] + ps[3][0];
    s2 = ps[0][1] + ps[1][1] + ps[2][1] + ps[3][1];
    const float mu = s * (1.f / 1024.f);
    const float var = s2 * (1.f / 1024.f) - mu * mu;
    float2 ms = {mu, rsqrtf(var + 1e-5f)};
    *(float2*)(musig + (size_t)row * 2) = ms;
  }
}

// ---------------- output GEMM with fused LN on A-stage ----------------
// A'[r][k] = ((hs[r][k]+skip[r][k]) - mu[r]) * rstd[r] * gamma[k] + beta[k]
__global__ __launch_bounds__(256) void gemm_outln(
    const _Float16* __restrict__ hs, const _Float16* __restrict__ rz,
    const float* __restrict__ musig, const float* __restrict__ gamma,
    const float* __restrict__ beta, const _Float16* __restrict__ Bw,
    const float* __restrict__ bias, float* __restrict__ C32, int t0) {
  __shared__ __align__(16) _Float16 As[128 * 64];
  __shared__ __align__(16) _Float16 Bs[128 * 64];
  const int tid = threadIdx.x, lane = tid & 63, wv = tid >> 6;
  const int wm = wv >> 1, wn = wv & 1;
  const int lj = lane & 15, lk = lane >> 4;
  const size_t rowA0 = (size_t)blockIdx.y * 128, colB0 = (size_t)blockIdx.x * 128;
  const int K = H_DIM;
  floatx4 acc[4][4] = {};
  for (int kb = 0; kb < K; kb += 64) {
    __syncthreads();
    // A-stage: reg-load hs+skip, normalize, cast fp16 -> LDS
#pragma unroll
    for (int i = 0; i < 4; ++i) {
      int u = i * 256 + tid;      // 0..1023
      int r = u >> 3, cg = u & 7; // row-in-tile, col-group (8 wide)
      size_t grow = rowA0 + r;
      int k0 = kb + cg * 8;
      half8 hv = *(const half8*)(hs + grow * 1024 + k0);
      half8 sv = *(const half8*)(rz + grow * 4096 + 3072 + k0);
      float2 ms = *(const float2*)(musig + grow * 2);
      float4 g0 = *(const float4*)(gamma + k0);
      float4 g1 = *(const float4*)(gamma + k0 + 4);
      float4 b0f = *(const float4*)(beta + k0);
      float4 b1f = *(const float4*)(beta + k0 + 4);
      half8 o;
      o[0] = (_Float16)(((float)hv[0] + (float)sv[0] - ms.x) * ms.y * g0.x + b0f.x);
      o[1] = (_Float16)(((float)hv[1] + (float)sv[1] - ms.x) * ms.y * g0.y + b0f.y);
      o[2] = (_Float16)(((float)hv[2] + (float)sv[2] - ms.x) * ms.y * g0.z + b0f.z);
      o[3] = (_Float16)(((float)hv[3] + (float)sv[3] - ms.x) * ms.y * g0.w + b0f.w);
      o[4] = (_Float16)(((float)hv[4] + (float)sv[4] - ms.x) * ms.y * g1.x + b1f.x);
      o[5] = (_Float16)(((float)hv[5] + (float)sv[5] - ms.x) * ms.y * g1.y + b1f.y);
      o[6] = (_Float16)(((float)hv[6] + (float)sv[6] - ms.x) * ms.y * g1.z + b1f.z);
      o[7] = (_Float16)(((float)hv[7] + (float)sv[7] - ms.x) * ms.y * g1.w + b1f.w);
      *(half8*)(As + r * 64 + cg * 8) = o;
    }
    // B-stage: weights via global_load_lds
#pragma unroll
    for (int i = 0; i < 4; ++i) {
      int q = i * 256 + tid;
      int r = q >> 3, cc = q & 7;
      gload_lds16(Bw + (colB0 + r) * (size_t)K + kb + cc * 8,
                  Bs + (size_t)(i * 4 + wv) * 512);
    }
    __syncthreads();
#pragma unroll
    for (int ks = 0; ks < 2; ++ks) {
      half8 af[4], bf[4];
#pragma unroll
      for (int am = 0; am < 4; ++am)
        af[am] = *(const half8*)(As + (wm * 64 + am * 16 + lj) * 64 + ks * 32 + lk * 8);
#pragma unroll
      for (int bn = 0; bn < 4; ++bn)
        bf[bn] = *(const half8*)(Bs + (wn * 64 + bn * 16 + lj) * 64 + ks * 32 + lk * 8);
#pragma unroll
      for (int am = 0; am < 4; ++am)
#pragma unroll
        for (int bn = 0; bn < 4; ++bn)
          acc[am][bn] =
              __builtin_amdgcn_mfma_f32_16x16x32_f16(af[am], bf[bn], acc[am][bn], 0, 0, 0);
    }
  }
#pragma unroll
  for (int am = 0; am < 4; ++am)
#pragma unroll
    for (int bn = 0; bn < 4; ++bn)
#pragma unroll
      for (int rr = 0; rr < 4; ++rr) {
        size_t grow = rowA0 + wm * 64 + am * 16 + lk * 4 + rr;
        size_t gcol = colB0 + wn * 64 + bn * 16 + lj;
        size_t tl = grow >> 7, b = grow & 127;
        C32[b * (size_t)(T_DIM * O_DIM) + (t0 + tl) * (size_t)O_DIM + gcol] =
            acc[am][bn][rr] + bias[gcol];
      }
}

// ---------------- host ----------------
extern "C" void kernel_launch(void* const* d_in, const int* in_sizes, int n_in,
                              void* d_out, int out_size, void* d_ws, size_t ws_size,
                              hipStream_t stream) {
  const float* x     = (const float*)d_in[0];
  const float* Wir   = (const float*)d_in[1];
  const float* bir   = (const float*)d_in[2];
  const float* Whr   = (const float*)d_in[3];
  const float* bhr   = (const float*)d_in[4];
  const float* Wiz   = (const float*)d_in[5];
  const float* biz   = (const float*)d_in[6];
  const float* Whz   = (const float*)d_in[7];
  const float* bhz   = (const float*)d_in[8];
  const float* Win   = (const float*)d_in[9];
  const float* bin_  = (const float*)d_in[10];
  const float* Whn   = (const float*)d_in[11];
  const float* bhn   = (const float*)d_in[12];
  const float* Wskip = (const float*)d_in[13];
  const float* bskip = (const float*)d_in[14];
  const float* gamma = (const float*)d_in[15];
  const float* beta  = (const float*)d_in[16];
  const float* Wout  = (const float*)d_in[17];
  const float* bout  = (const float*)d_in[18];
  float* out = (float*)d_out;

  char* ws = (char*)d_ws;
  size_t off = 0;
  auto alloc = [&](size_t bytes) -> char* {
    char* p = ws + off;
    off += (bytes + 255) & ~(size_t)255;
    return p;
  };
  _Float16* x16    = (_Float16*)alloc((size_t)TC * 128 * 512 * 2);
  _Float16* Wcat   = (_Float16*)alloc((size_t)4096 * 512 * 2);
  _Float16* Whcat  = (_Float16*)alloc((size_t)3072 * 1024 * 2);
  _Float16* Wout16 = (_Float16*)alloc((size_t)512 * 1024 * 2);
  float*    bcat   = (float*)alloc(4096 * 4);
  _Float16* rznx   = (_Float16*)alloc((size_t)TC * 128 * 4096 * 2);
  _Float16* h16    = (_Float16*)alloc((size_t)2 * 128 * 1024 * 2);
  float*    h32    = (float*)alloc((size_t)128 * 1024 * 4);
  _Float16* hs16   = (_Float16*)alloc((size_t)TC * 128 * 1024 * 2);
  float*    musig  = (float*)alloc((size_t)TC * 128 * 2 * 4);
  int*      flags  = (int*)alloc(8 * 32 * 32 * sizeof(int));

  k_cvt<<<512, 256, 0, stream>>>(Wir, Wcat + 0 * 524288, 131072);
  k_cvt<<<512, 256, 0, stream>>>(Wiz, Wcat + 1 * 524288, 131072);
  k_cvt<<<512, 256, 0, stream>>>(Win, Wcat + 2 * 524288, 131072);
  k_cvt<<<512, 256, 0, stream>>>(Wskip, Wcat + 3 * 524288, 131072);
  k_cvt<<<1024, 256, 0, stream>>>(Whr, Whcat + 0 * 1048576, 262144);
  k_cvt<<<1024, 256, 0, stream>>>(Whz, Whcat + 1 * 1048576, 262144);
  k_cvt<<<1024, 256, 0, stream>>>(Whn, Whcat + 2 * 1048576, 262144);
  k_cvt<<<512, 256, 0, stream>>>(Wout, Wout16, 131072);
  build_bcat<<<16, 256, 0, stream>>>(bir, biz, bin_, bskip, bcat);
  hipMemsetAsync(h16, 0, (size_t)2 * 128 * 1024 * 2, stream);
  hipMemsetAsync(h32, 0, (size_t)128 * 1024 * 4, stream);
  hipMemsetAsync(flags, 0, 8 * 32 * 32 * sizeof(int), stream);

  for (int c = 0; c < NCHUNK; ++c) {
    int t0 = c * TC;
    k_cvt_x<<<(TC * 128 * 512 / 4) / 256, 256, 0, stream>>>(x, x16, t0);
    gemm_f16<<<dim3(4096 / 128, TC * 128 / 128), 256, 0, stream>>>(
        x16, Wcat, bcat, rznx, TC * 128, 4096, 512);
    scan_kernel<<<256, 384, 0, stream>>>(rznx, Whcat, bhr, bhz, bhn, h16, h32, hs16, flags, c);
    ln_stats<<<TC * 128, 256, 0, stream>>>(hs16, rznx, musig);
    gemm_outln<<<dim3(4, 64), 256, 0, stream>>>(hs16, rznx, musig, gamma, beta,
                                                Wout16, bout, out, t0);
  }
}